// Round 2
// baseline (201.763 us; speedup 1.0000x reference)
//
#include <hip/hip_runtime.h>

#define D 64
#define L 10
#define C 256

__device__ inline float wave_sum(float v) {
#pragma unroll
  for (int off = 32; off > 0; off >>= 1) v += __shfl_xor(v, off);
  return v;
}
__device__ inline float wave_max(float v) {
#pragma unroll
  for (int off = 32; off > 0; off >>= 1) v = fmaxf(v, __shfl_xor(v, off));
  return v;
}

// Kt[k*C+c] = (cluster_emb @ Wk)^T ; V[c*D+d] = cluster_emb @ Wv
__global__ void kv_precompute(const float* __restrict__ cl,
                              const float* __restrict__ Wk,
                              const float* __restrict__ Wv,
                              float* __restrict__ Kt,
                              float* __restrict__ V) {
  int idx = blockIdx.x * blockDim.x + threadIdx.x;  // 0 .. 2*C*D-1
  if (idx >= 2 * C * D) return;
  int which = idx >> 14;  // C*D = 16384
  int cd = idx & (C * D - 1);
  int c = cd >> 6, d = cd & 63;
  const float* __restrict__ W = which ? Wv : Wk;
  float acc = 0.f;
#pragma unroll
  for (int k = 0; k < D; ++k) acc += cl[c * D + k] * W[k * D + d];
  if (which) V[c * D + d] = acc;
  else       Kt[d * C + c] = acc;  // transposed store
}

__global__ __launch_bounds__(256) void filter_main(
    const int* __restrict__ items,        // [U,L]
    const float* __restrict__ time_embs,  // [U,L,D]
    const float* __restrict__ ue_g,       // [U,D]
    const float* __restrict__ ie_g,       // [N,D]
    const float* __restrict__ wf_g,       // [U,L,D]
    const float* __restrict__ Wq,         // [D,D]
    const float* __restrict__ Kt,         // [D,C] transposed K
    const float* __restrict__ Vmat,       // [C,D]
    const int* __restrict__ users,
    const int* __restrict__ pos_items,
    const int* __restrict__ neg_items,
    const float* __restrict__ a1p,
    const float* __restrict__ a2p,
    const float* __restrict__ a3p,
    float* __restrict__ out, int B) {
  __shared__ float s_ue[D];
  __shared__ int s_it[L];
  __shared__ float s_short[L][D];
  __shared__ float s_q[L][D];
  __shared__ float s_attn[L][C];
  __shared__ float s_red[L][4];
  __shared__ float s_shorted[L][D];
  __shared__ float s_sl[L];
  __shared__ float s_part[4][D];

  const int b = blockIdx.x;
  const int tid = threadIdx.x;
  const int w = tid >> 6;     // wave id 0..3
  const int lane = tid & 63;  // = d for per-dim phases
  const int u = users[b];
  const int BD = B * D;

  // fused pos/neg gathers (independent of everything else)
  if (tid >= 64 && tid < 128) {
    int p = pos_items[b];
    out[BD + b * D + (tid - 64)] = ie_g[p * D + (tid - 64)];
  } else if (tid >= 128 && tid < 192) {
    int p = neg_items[b];
    out[2 * BD + b * D + (tid - 128)] = ie_g[p * D + (tid - 128)];
  }

  if (tid < D) s_ue[tid] = ue_g[u * D + tid];
  if (tid < L) s_it[tid] = items[u * L + tid];
  __syncthreads();

  // short[l][d] = ue[d] + item_emb[items[l]][d] + time_embs[u][l][d]
  for (int idx = tid; idx < L * D; idx += 256) {
    int l = idx >> 6, d = idx & 63;
    s_short[l][d] = s_ue[d] + ie_g[s_it[l] * D + d] + time_embs[(u * L + l) * D + d];
  }
  __syncthreads();

  // Q[l][d] = (short[l] . Wq[:,d]) * (1/sqrt(D))
  for (int idx = tid; idx < L * D; idx += 256) {
    int l = idx >> 6, d = idx & 63;
    float acc = 0.f;
#pragma unroll
    for (int k = 0; k < D; ++k) acc += s_short[l][k] * Wq[k * D + d];
    s_q[l][d] = acc * 0.125f;  // 1/sqrt(64)
  }
  __syncthreads();

  // scores: thread c = tid computes scores[l][c] for all l; Kt read coalesced
  float sc[L];
#pragma unroll
  for (int l = 0; l < L; ++l) sc[l] = 0.f;
  {
    const int c = tid;
#pragma unroll 8
    for (int k = 0; k < D; ++k) {
      float kv = Kt[k * C + c];
#pragma unroll
      for (int l = 0; l < L; ++l) sc[l] += s_q[l][k] * kv;
    }
  }
  // softmax over c (256 threads)
#pragma unroll
  for (int l = 0; l < L; ++l) {
    float v = wave_max(sc[l]);
    if (lane == 0) s_red[l][w] = v;
  }
  __syncthreads();
  float e[L];
#pragma unroll
  for (int l = 0; l < L; ++l) {
    float m = fmaxf(fmaxf(s_red[l][0], s_red[l][1]), fmaxf(s_red[l][2], s_red[l][3]));
    e[l] = __expf(sc[l] - m);
  }
  __syncthreads();  // s_red reuse
#pragma unroll
  for (int l = 0; l < L; ++l) {
    float v = wave_sum(e[l]);
    if (lane == 0) s_red[l][w] = v;
  }
  __syncthreads();
#pragma unroll
  for (int l = 0; l < L; ++l) {
    float s = (s_red[l][0] + s_red[l][1]) + (s_red[l][2] + s_red[l][3]);
    s_attn[l][tid] = e[l] * __frcp_rn(s);
  }
  __syncthreads();

  // shorted[l][d] = sum_c attn[l][c] * V[c][d]; V read direct from L2 (coalesced)
  // wave w handles l = w, w+4, (w+8 if w<2); lane = d
  float acc0 = 0.f, acc1 = 0.f, acc2 = 0.f;
#pragma unroll 8
  for (int c = 0; c < C; ++c) {
    float vv = Vmat[c * D + lane];
    acc0 += s_attn[w][c] * vv;
    acc1 += s_attn[w + 4][c] * vv;
    if (w < 2) acc2 += s_attn[w + 8][c] * vv;
  }
  s_shorted[w][lane] = acc0;
  s_shorted[w + 4][lane] = acc1;
  if (w < 2) s_shorted[w + 8][lane] = acc2;
  __syncthreads();

  // s_l = ue . shorted[l]
  for (int l = w; l < L; l += 4) {
    float p = s_ue[lane] * s_shorted[l][lane];
    p = wave_sum(p);
    if (lane == 0) s_sl[l] = p;
  }
  __syncthreads();

  // nu[d] = sum_l s_l[l]*wf[u][l][d], split across waves
  {
    float nu = 0.f;
    for (int l = w; l < L; l += 4) nu += s_sl[l] * wf_g[(u * L + l) * D + lane];
    s_part[w][lane] = nu;
  }
  __syncthreads();

  if (tid < D) {
    float a1 = *a1p, a2 = *a2p, a3 = *a3p;
    float nu = (s_part[0][tid] + s_part[1][tid]) + (s_part[2][tid] + s_part[3][tid]);
    out[b * D + tid] = a3 * (a1 * s_ue[tid] + a2 * nu);
  }
}

extern "C" void kernel_launch(void* const* d_in, const int* in_sizes, int n_in,
                              void* d_out, int out_size, void* d_ws, size_t ws_size,
                              hipStream_t stream) {
  const int* items = (const int*)d_in[0];
  const float* time_embs = (const float*)d_in[1];
  const float* user_emb = (const float*)d_in[2];
  const float* item_emb = (const float*)d_in[3];
  const float* cluster = (const float*)d_in[4];
  const float* wf = (const float*)d_in[5];
  const float* Wq = (const float*)d_in[6];
  const float* Wk = (const float*)d_in[7];
  const float* Wv = (const float*)d_in[8];
  const int* users = (const int*)d_in[9];
  const int* pos = (const int*)d_in[10];
  const int* neg = (const int*)d_in[11];
  const float* a1 = (const float*)d_in[12];
  const float* a2 = (const float*)d_in[13];
  const float* a3 = (const float*)d_in[14];
  const int B = in_sizes[9];

  float* Kt = (float*)d_ws;        // [D*C]
  float* V = Kt + C * D;           // [C*D]
  hipLaunchKernelGGL(kv_precompute, dim3((2 * C * D + 255) / 256), dim3(256), 0, stream,
                     cluster, Wk, Wv, Kt, V);
  hipLaunchKernelGGL(filter_main, dim3(B), dim3(256), 0, stream,
                     items, time_embs, user_emb, item_emb, wf, Wq,
                     Kt, V, users, pos, neg, a1, a2, a3,
                     (float*)d_out, B);
}

// Round 3
// 79.492 us; speedup vs baseline: 2.5382x; 2.5382x over previous
//
#include <hip/hip_runtime.h>

#define D 64
#define L 10
#define C 256
#define G 2  // users per block

__device__ inline float wave_max(float v) {
#pragma unroll
  for (int off = 32; off > 0; off >>= 1) v = fmaxf(v, __shfl_xor(v, off));
  return v;
}
__device__ inline float wave_sum(float v) {
#pragma unroll
  for (int off = 32; off > 0; off >>= 1) v += __shfl_xor(v, off);
  return v;
}

// stage 1: Kt[d*C+c] = (cluster@Wk)[c][d], Vt[d*C+c] = (cluster@Wv)[c][d]
__global__ void kv_precompute(const float* __restrict__ cl,
                              const float* __restrict__ Wk,
                              const float* __restrict__ Wv,
                              float* __restrict__ Kt,
                              float* __restrict__ Vt) {
  int idx = blockIdx.x * blockDim.x + threadIdx.x;  // 0 .. 2*C*D-1
  if (idx >= 2 * C * D) return;
  int which = idx >> 14;  // C*D = 16384
  int cd = idx & (C * D - 1);
  int c = cd >> 6, d = cd & 63;
  const float* __restrict__ W = which ? Wv : Wk;
  float acc = 0.f;
#pragma unroll
  for (int k = 0; k < D; ++k) acc += cl[c * D + k] * W[k * D + d];
  if (which) Vt[d * C + c] = acc;
  else       Kt[d * C + c] = acc;
}

// stage 2: WqKt[j*C+c] = 0.125 * sum_k Wq[j][k] * Kt[k*C+c]   ( = (Wq@K^T)/sqrt(D) )
__global__ void wqk_precompute(const float* __restrict__ Wq,
                               const float* __restrict__ Kt,
                               float* __restrict__ WqKt) {
  int idx = blockIdx.x * blockDim.x + threadIdx.x;  // 0 .. C*D-1
  if (idx >= C * D) return;
  int c = idx & (C - 1), j = idx >> 8;
  float acc = 0.f;
#pragma unroll
  for (int k = 0; k < D; ++k) acc += Wq[j * D + k] * Kt[k * C + c];
  WqKt[j * C + c] = 0.125f * acc;
}

__global__ __launch_bounds__(256, 4) void filter_main(
    const int* __restrict__ items,        // [U,L]
    const float* __restrict__ time_embs,  // [U,L,D]
    const float* __restrict__ ue_g,       // [U,D]
    const float* __restrict__ ie_g,       // [N,D]
    const float* __restrict__ wf_g,       // [U,L,D]
    const float* __restrict__ WqKt,       // [D,C]
    const float* __restrict__ Vt,         // [D,C]
    const int* __restrict__ users,
    const int* __restrict__ pos_items,
    const int* __restrict__ neg_items,
    const float* __restrict__ a1p,
    const float* __restrict__ a2p,
    const float* __restrict__ a3p,
    float* __restrict__ out, int B) {
  __shared__ float4 s_short[G][L][16];   // short vectors, float4 over d
  __shared__ float4 s_ue4[G][16];        // user embeddings
  __shared__ int s_it[G][L];
  __shared__ float4 s_red[G][L][4];      // per-wave (m, S, T, _)
  __shared__ float s_part[4][G][D];

  const int b = blockIdx.x;
  const int tid = threadIdx.x;
  const int w = tid >> 6, lane = tid & 63;
  const int BD = B * D;
  const int u0 = users[b * G];      // uniform -> SGPR
  const int u1 = users[b * G + 1];

  // fused pos/neg gathers: tid 0..127 -> pos rows, 128..255 -> neg rows
  {
    int g = (tid >> 6) & 1;
    int row = b * G + g;
    if (tid < 128) out[BD + row * D + lane]     = ie_g[pos_items[row] * D + lane];
    else           out[2 * BD + row * D + lane] = ie_g[neg_items[row] * D + lane];
  }

  if (tid < G * D) {  // 128 threads: load user embeddings
    int g = tid >> 6;
    ((float*)s_ue4)[g * D + lane] = ue_g[(g ? u1 : u0) * D + lane];
  }
  if (tid < G * L) {  // 20 threads: item ids
    int g = tid / L, l = tid - g * L;
    s_it[g][l] = items[(g ? u1 : u0) * L + l];
  }
  __syncthreads();

  // short[g][l][d] = ue + item_emb[it] + time_emb  (float4; 320 work items)
  for (int idx = tid; idx < G * L * 16; idx += 256) {
    int g = idx / 160, rem = idx - g * 160, l = rem >> 4, q4 = rem & 15;
    int u = g ? u1 : u0;
    float4 te = ((const float4*)time_embs)[(u * L + l) * 16 + q4];
    float4 ie = ((const float4*)ie_g)[s_it[g][l] * 16 + q4];
    float4 ue = s_ue4[g][q4];
    float4 r;
    r.x = ue.x + ie.x + te.x;
    r.y = ue.y + ie.y + te.y;
    r.z = ue.z + ie.z + te.z;
    r.w = ue.w + ie.w + te.w;
    s_short[g][l][q4] = r;
  }
  __syncthreads();

  // merged loop over k: scores[g][l][c] += short[g][l][k]*WqKt[k][c]
  //                     vu[g]          += ue[g][k]*Vt[k][c]
  float sc[G][L];
  float vu[G];
#pragma unroll
  for (int g = 0; g < G; ++g) {
    vu[g] = 0.f;
#pragma unroll
    for (int l = 0; l < L; ++l) sc[g][l] = 0.f;
  }
  const int c = tid;
#pragma unroll 4
  for (int k0 = 0; k0 < 16; ++k0) {
    float kt0 = WqKt[(k0 * 4 + 0) * C + c];
    float kt1 = WqKt[(k0 * 4 + 1) * C + c];
    float kt2 = WqKt[(k0 * 4 + 2) * C + c];
    float kt3 = WqKt[(k0 * 4 + 3) * C + c];
    float vt0 = Vt[(k0 * 4 + 0) * C + c];
    float vt1 = Vt[(k0 * 4 + 1) * C + c];
    float vt2 = Vt[(k0 * 4 + 2) * C + c];
    float vt3 = Vt[(k0 * 4 + 3) * C + c];
    float4 ua = s_ue4[0][k0];
    float4 ub = s_ue4[1][k0];
    vu[0] += vt0 * ua.x + vt1 * ua.y + vt2 * ua.z + vt3 * ua.w;
    vu[1] += vt0 * ub.x + vt1 * ub.y + vt2 * ub.z + vt3 * ub.w;
#pragma unroll
    for (int g = 0; g < G; ++g)
#pragma unroll
      for (int l = 0; l < L; ++l) {
        float4 q = s_short[g][l][k0];
        sc[g][l] += q.x * kt0 + q.y * kt1 + q.z * kt2 + q.w * kt3;
      }
  }

  // per-wave softmax stats: m_w, S_w = sum e, T_w = sum e*vu   (one barrier)
#pragma unroll
  for (int g = 0; g < G; ++g)
#pragma unroll
    for (int l = 0; l < L; ++l) {
      float m = wave_max(sc[g][l]);
      float e = __expf(sc[g][l] - m);
      float s = wave_sum(e);
      float t = wave_sum(e * vu[g]);
      if (lane == 0) s_red[g][l][w] = make_float4(m, s, t, 0.f);
    }
  __syncthreads();

  // combine stats -> s_l = T/S ; nu[g][d] += s_l * wf[u_g][l][d]
  // wave w handles pairs p = w*5 .. w*5+4  (p = g*10 + l)
  float nu0 = 0.f, nu1 = 0.f;
#pragma unroll
  for (int i = 0; i < 5; ++i) {
    int p = w * 5 + i;
    int g = (p >= L) ? 1 : 0;
    int l = p - g * L;
    float4 r0 = s_red[g][l][0], r1 = s_red[g][l][1];
    float4 r2 = s_red[g][l][2], r3 = s_red[g][l][3];
    float M = fmaxf(fmaxf(r0.x, r1.x), fmaxf(r2.x, r3.x));
    float e0 = __expf(r0.x - M), e1 = __expf(r1.x - M);
    float e2 = __expf(r2.x - M), e3 = __expf(r3.x - M);
    float S = r0.y * e0 + r1.y * e1 + r2.y * e2 + r3.y * e3;
    float T = r0.z * e0 + r1.z * e1 + r2.z * e2 + r3.z * e3;
    float sl = T / S;
    int u = g ? u1 : u0;
    float wfv = wf_g[(u * L + l) * D + lane];
    if (g) nu1 += sl * wfv;
    else   nu0 += sl * wfv;
  }
  s_part[w][0][lane] = nu0;
  s_part[w][1][lane] = nu1;
  __syncthreads();

  if (tid < G * D) {
    int g = tid >> 6;
    float nu = (s_part[0][g][lane] + s_part[1][g][lane]) +
               (s_part[2][g][lane] + s_part[3][g][lane]);
    float a1 = *a1p, a2 = *a2p, a3 = *a3p;
    float ue = ((float*)s_ue4)[g * D + lane];
    out[(b * G + g) * D + lane] = a3 * (a1 * ue + a2 * nu);
  }
}

extern "C" void kernel_launch(void* const* d_in, const int* in_sizes, int n_in,
                              void* d_out, int out_size, void* d_ws, size_t ws_size,
                              hipStream_t stream) {
  const int* items = (const int*)d_in[0];
  const float* time_embs = (const float*)d_in[1];
  const float* user_emb = (const float*)d_in[2];
  const float* item_emb = (const float*)d_in[3];
  const float* cluster = (const float*)d_in[4];
  const float* wf = (const float*)d_in[5];
  const float* Wq = (const float*)d_in[6];
  const float* Wk = (const float*)d_in[7];
  const float* Wv = (const float*)d_in[8];
  const int* users = (const int*)d_in[9];
  const int* pos = (const int*)d_in[10];
  const int* neg = (const int*)d_in[11];
  const float* a1 = (const float*)d_in[12];
  const float* a2 = (const float*)d_in[13];
  const float* a3 = (const float*)d_in[14];
  const int B = in_sizes[9];

  float* Kt = (float*)d_ws;      // [D*C]
  float* Vt = Kt + C * D;        // [D*C]
  float* WqKt = Vt + C * D;      // [D*C]
  hipLaunchKernelGGL(kv_precompute, dim3((2 * C * D + 255) / 256), dim3(256), 0, stream,
                     cluster, Wk, Wv, Kt, Vt);
  hipLaunchKernelGGL(wqk_precompute, dim3((C * D + 255) / 256), dim3(256), 0, stream,
                     Wq, Kt, WqKt);
  hipLaunchKernelGGL(filter_main, dim3(B / G), dim3(256), 0, stream,
                     items, time_embs, user_emb, item_emb, wf,
                     WqKt, Vt, users, pos, neg, a1, a2, a3,
                     (float*)d_out, B);
}

// Round 4
// 57.901 us; speedup vs baseline: 3.4847x; 1.3729x over previous
//
#include <hip/hip_runtime.h>

#define D 64
#define L 10
#define C 256
#define G 2

typedef __attribute__((ext_vector_type(8))) short bf16x8;
typedef __attribute__((ext_vector_type(4))) float f32x4;

__device__ inline short f2bf(float f) {
  unsigned u = __float_as_uint(f);
  u = (u + 0x7FFFu + ((u >> 16) & 1u)) >> 16;
  return (short)u;
}
__device__ inline float4 add3(float4 a, float4 b, float4 c) {
  return make_float4(a.x + b.x + c.x, a.y + b.y + c.y, a.z + b.z + c.z, a.w + b.w + c.w);
}
__device__ inline bf16x8 pack8(float4 a, float4 b) {
  bf16x8 r;
  r[0] = f2bf(a.x); r[1] = f2bf(a.y); r[2] = f2bf(a.z); r[3] = f2bf(a.w);
  r[4] = f2bf(b.x); r[5] = f2bf(b.y); r[6] = f2bf(b.z); r[7] = f2bf(b.w);
  return r;
}

// P1: Kc[c][j] = (cluster@Wk)[c][j] fp32 ; Bf[c][64+d] = bf16((cluster@Wv)[c][d])
__global__ void pre1(const float* __restrict__ cl, const float* __restrict__ Wk,
                     const float* __restrict__ Wv, float* __restrict__ Kc,
                     short* __restrict__ Bf) {
  int idx = blockIdx.x * 256 + threadIdx.x;
  if (idx >= 2 * C * D) return;
  int which = idx >> 14;
  int cd = idx & (C * D - 1);
  int c = cd >> 6, d = cd & 63;
  const float* __restrict__ W = which ? Wv : Wk;
  float acc = 0.f;
#pragma unroll
  for (int k = 0; k < D; ++k) acc += cl[c * D + k] * W[k * D + d];
  if (which) Bf[c * 128 + 64 + d] = f2bf(acc);
  else       Kc[c * D + d] = acc;
}

// P2: Bf[c][k] = bf16( 0.125 * sum_j Wq[k][j] * Kc[c][j] )
__global__ void pre2(const float* __restrict__ Wq, const float* __restrict__ Kc,
                     short* __restrict__ Bf) {
  int idx = blockIdx.x * 256 + threadIdx.x;
  if (idx >= C * D) return;
  int c = idx >> 6, k = idx & 63;
  float acc = 0.f;
#pragma unroll
  for (int j = 0; j < D; ++j) acc += Wq[k * D + j] * Kc[c * D + j];
  Bf[c * 128 + k] = f2bf(0.125f * acc);
}

__global__ __launch_bounds__(256) void filter_main(
    const int* __restrict__ items,        // [U,L]
    const float* __restrict__ te,         // [U,L,D]
    const float* __restrict__ ue_g,       // [U,D]
    const float* __restrict__ ie_g,       // [N,D]
    const float* __restrict__ wf_g,       // [U,L,D]
    const short* __restrict__ Bf,         // [C][128] bf16: k<64 WqKt, k>=64 V
    const int* __restrict__ users,
    const int* __restrict__ pos_items,
    const int* __restrict__ neg_items,
    const float* __restrict__ a1p, const float* __restrict__ a2p,
    const float* __restrict__ a3p,
    float* __restrict__ out, int B) {
  __shared__ float4 s_red[20][4];   // per-row per-wave (m, S, T, _)
  __shared__ float s_part[4][G][D];

  const int b = blockIdx.x, tid = threadIdx.x;
  const int w = tid >> 6, lane = tid & 63;
  const int u0 = users[b * G], u1 = users[b * G + 1];
  const int BD = B * D;

  // fused pos/neg gathers
  {
    int gg = (tid >> 6) & 1;
    int row = b * G + gg;
    if (tid < 128) out[BD + row * D + lane]     = ie_g[pos_items[row] * D + lane];
    else           out[2 * BD + row * D + lane] = ie_g[neg_items[row] * D + lane];
  }

  const int r0 = lane & 15;   // A-frag row-in-tile; also B-frag col-in-tile
  const int kb = lane >> 4;   // k-chunk (8 elems) within K=32 step
  const float4* te4 = (const float4*)te;
  const float4* ie4 = (const float4*)ie_g;
  const float4* ue4 = (const float4*)ue_g;

  // ---- A fragments (rows: 0-9 g0 l0-9; 10-15 g1 l0-5; 16-19 g1 l6-9;
  //                   20 ue0; 21 ue1; 22-31 zero). K: 0-63 short, 64-127 ue.
  bf16x8 a0s0, a0s1;
  bf16x8 a1s0 = {}, a1s1 = {}, a1s2 = {}, a1s3 = {};
  {
    int gg = (r0 >= 10) ? 1 : 0;
    int lr = r0 - gg * 10;
    int uu = gg ? u1 : u0;
    int it = items[uu * L + lr];
    int tb = (uu * L + lr) * 16 + kb * 2;
    int ib = it * 16 + kb * 2;
    int ub = uu * 16 + kb * 2;
    float4 x0 = add3(te4[tb],     ie4[ib],     ue4[ub]);
    float4 x1 = add3(te4[tb + 1], ie4[ib + 1], ue4[ub + 1]);
    float4 x2 = add3(te4[tb + 8], ie4[ib + 8], ue4[ub + 8]);
    float4 x3 = add3(te4[tb + 9], ie4[ib + 9], ue4[ub + 9]);
    a0s0 = pack8(x0, x1);
    a0s1 = pack8(x2, x3);
  }
  if (r0 < 4) {  // rows 16-19: g1, l = 6+r0
    int lr = 6 + r0;
    int it = items[u1 * L + lr];
    int tb = (u1 * L + lr) * 16 + kb * 2;
    int ib = it * 16 + kb * 2;
    int ub = u1 * 16 + kb * 2;
    float4 x0 = add3(te4[tb],     ie4[ib],     ue4[ub]);
    float4 x1 = add3(te4[tb + 1], ie4[ib + 1], ue4[ub + 1]);
    float4 x2 = add3(te4[tb + 8], ie4[ib + 8], ue4[ub + 8]);
    float4 x3 = add3(te4[tb + 9], ie4[ib + 9], ue4[ub + 9]);
    a1s0 = pack8(x0, x1);
    a1s1 = pack8(x2, x3);
  } else if (r0 < 6) {  // rows 20/21: ue in k 64..127
    int uu = (r0 == 5) ? u1 : u0;
    int ub = uu * 16 + kb * 2;
    a1s2 = pack8(ue4[ub],     ue4[ub + 1]);
    a1s3 = pack8(ue4[ub + 8], ue4[ub + 9]);
  }

  // ---- GEMM: wave w covers cols w*64 .. w*64+63 (4 N-tiles)
  f32x4 zz = {0.f, 0.f, 0.f, 0.f};
  f32x4 acc0[4] = {zz, zz, zz, zz};
  f32x4 acc1[4] = {zz, zz, zz, zz};
#pragma unroll
  for (int nt = 0; nt < 4; ++nt) {
    int c0 = (w * 4 + nt) * 16 + r0;
    const bf16x8* bp = (const bf16x8*)(Bf + c0 * 128 + kb * 8);
    bf16x8 b0 = bp[0], b1 = bp[4], b2 = bp[8], b3 = bp[12];
    acc0[nt] = __builtin_amdgcn_mfma_f32_16x16x32_bf16(a0s0, b0, acc0[nt], 0, 0, 0);
    acc0[nt] = __builtin_amdgcn_mfma_f32_16x16x32_bf16(a0s1, b1, acc0[nt], 0, 0, 0);
    acc1[nt] = __builtin_amdgcn_mfma_f32_16x16x32_bf16(a1s0, b0, acc1[nt], 0, 0, 0);
    acc1[nt] = __builtin_amdgcn_mfma_f32_16x16x32_bf16(a1s1, b1, acc1[nt], 0, 0, 0);
    acc1[nt] = __builtin_amdgcn_mfma_f32_16x16x32_bf16(a1s2, b2, acc1[nt], 0, 0, 0);
    acc1[nt] = __builtin_amdgcn_mfma_f32_16x16x32_bf16(a1s3, b3, acc1[nt], 0, 0, 0);
  }

  // ---- in-register softmax stats over this wave's 64 cols
  const int q = lane >> 4, col16 = lane & 15;
  // vu rows: row20 = acc1[nt][0] @ lanes 16-31; row21 = acc1[nt][1] @ lanes 16-31
  float vub0[4], vub1[4];
#pragma unroll
  for (int nt = 0; nt < 4; ++nt) {
    vub0[nt] = __shfl(acc1[nt][0], 16 + col16, 64);
    vub1[nt] = __shfl(acc1[nt][1], 16 + col16, 64);
  }
#pragma unroll
  for (int mt = 0; mt < 2; ++mt) {
#pragma unroll
    for (int j = 0; j < 4; ++j) {
      float v0 = mt ? acc1[0][j] : acc0[0][j];
      float v1 = mt ? acc1[1][j] : acc0[1][j];
      float v2 = mt ? acc1[2][j] : acc0[2][j];
      float v3 = mt ? acc1[3][j] : acc0[3][j];
      int row = mt * 16 + q * 4 + j;
      float m = fmaxf(fmaxf(v0, v1), fmaxf(v2, v3));
      m = fmaxf(m, __shfl_xor(m, 1, 64));
      m = fmaxf(m, __shfl_xor(m, 2, 64));
      m = fmaxf(m, __shfl_xor(m, 4, 64));
      m = fmaxf(m, __shfl_xor(m, 8, 64));
      float e0 = __expf(v0 - m), e1 = __expf(v1 - m);
      float e2 = __expf(v2 - m), e3 = __expf(v3 - m);
      bool gg = row >= 10;
      float S = (e0 + e1) + (e2 + e3);
      float T = e0 * (gg ? vub1[0] : vub0[0]) + e1 * (gg ? vub1[1] : vub0[1]) +
                e2 * (gg ? vub1[2] : vub0[2]) + e3 * (gg ? vub1[3] : vub0[3]);
      S += __shfl_xor(S, 1, 64); S += __shfl_xor(S, 2, 64);
      S += __shfl_xor(S, 4, 64); S += __shfl_xor(S, 8, 64);
      T += __shfl_xor(T, 1, 64); T += __shfl_xor(T, 2, 64);
      T += __shfl_xor(T, 4, 64); T += __shfl_xor(T, 8, 64);
      if (col16 == 0 && (mt == 0 || q == 0) && row < 20)
        s_red[row][w] = make_float4(m, S, T, 0.f);
    }
  }
  __syncthreads();

  // ---- combine wave stats, s_l = T/S, nu accumulation (wave w: rows w*5..w*5+4)
  float nu0 = 0.f, nu1 = 0.f;
#pragma unroll
  for (int i = 0; i < 5; ++i) {
    int p = w * 5 + i;
    float4 r0v = s_red[p][0], r1v = s_red[p][1], r2v = s_red[p][2], r3v = s_red[p][3];
    float M = fmaxf(fmaxf(r0v.x, r1v.x), fmaxf(r2v.x, r3v.x));
    float e0 = __expf(r0v.x - M), e1 = __expf(r1v.x - M);
    float e2 = __expf(r2v.x - M), e3 = __expf(r3v.x - M);
    float S = r0v.y * e0 + r1v.y * e1 + r2v.y * e2 + r3v.y * e3;
    float T = r0v.z * e0 + r1v.z * e1 + r2v.z * e2 + r3v.z * e3;
    float sl = T / S;
    int gg = (p >= 10) ? 1 : 0;
    int lr = p - gg * 10;
    int uu = gg ? u1 : u0;
    float wfv = wf_g[(uu * L + lr) * D + lane];
    if (gg) nu1 += sl * wfv;
    else    nu0 += sl * wfv;
  }
  s_part[w][0][lane] = nu0;
  s_part[w][1][lane] = nu1;
  __syncthreads();

  if (tid < G * D) {
    int gg = tid >> 6;
    float nu = (s_part[0][gg][lane] + s_part[1][gg][lane]) +
               (s_part[2][gg][lane] + s_part[3][gg][lane]);
    int uu = gg ? u1 : u0;
    float a1 = *a1p, a2 = *a2p, a3 = *a3p;
    float ue = ue_g[uu * D + lane];
    out[(b * G + gg) * D + lane] = a3 * (a1 * ue + a2 * nu);
  }
}

extern "C" void kernel_launch(void* const* d_in, const int* in_sizes, int n_in,
                              void* d_out, int out_size, void* d_ws, size_t ws_size,
                              hipStream_t stream) {
  const int* items = (const int*)d_in[0];
  const float* time_embs = (const float*)d_in[1];
  const float* user_emb = (const float*)d_in[2];
  const float* item_emb = (const float*)d_in[3];
  const float* cluster = (const float*)d_in[4];
  const float* wf = (const float*)d_in[5];
  const float* Wq = (const float*)d_in[6];
  const float* Wk = (const float*)d_in[7];
  const float* Wv = (const float*)d_in[8];
  const int* users = (const int*)d_in[9];
  const int* pos = (const int*)d_in[10];
  const int* neg = (const int*)d_in[11];
  const float* a1 = (const float*)d_in[12];
  const float* a2 = (const float*)d_in[13];
  const float* a3 = (const float*)d_in[14];
  const int B = in_sizes[9];

  float* Kc = (float*)d_ws;                               // [C*D] fp32
  short* Bf = (short*)((char*)d_ws + C * D * sizeof(float));  // [C*128] bf16
  hipLaunchKernelGGL(pre1, dim3((2 * C * D + 255) / 256), dim3(256), 0, stream,
                     cluster, Wk, Wv, Kc, Bf);
  hipLaunchKernelGGL(pre2, dim3((C * D + 255) / 256), dim3(256), 0, stream,
                     Wq, Kc, Bf);
  hipLaunchKernelGGL(filter_main, dim3(B / G), dim3(256), 0, stream,
                     items, time_embs, user_emb, item_emb, wf, Bf,
                     users, pos, neg, a1, a2, a3, (float*)d_out, B);
}

// Round 5
// 49.162 us; speedup vs baseline: 4.1041x; 1.1778x over previous
//
#include <hip/hip_runtime.h>

#define D 64
#define L 10
#define C 256
#define G 4

typedef __attribute__((ext_vector_type(8))) short bf16x8;
typedef __attribute__((ext_vector_type(4))) float f32x4;

__device__ inline short f2bf(float f) {
  unsigned u = __float_as_uint(f);
  u = (u + 0x7FFFu + ((u >> 16) & 1u)) >> 16;
  return (short)u;
}
__device__ inline float4 add3(float4 a, float4 b, float4 c) {
  return make_float4(a.x + b.x + c.x, a.y + b.y + c.y, a.z + b.z + c.z, a.w + b.w + c.w);
}
__device__ inline bf16x8 pack8(float4 a, float4 b) {
  bf16x8 r;
  r[0] = f2bf(a.x); r[1] = f2bf(a.y); r[2] = f2bf(a.z); r[3] = f2bf(a.w);
  r[4] = f2bf(b.x); r[5] = f2bf(b.y); r[6] = f2bf(b.z); r[7] = f2bf(b.w);
  return r;
}

// One pre-kernel. Blocks 0..63: Bf[c][k] = bf16(cl[c]·M1[:,k]) with
// M1 = 0.125*Wk@Wq^T recomputed per-block in LDS. Blocks 64..127:
// Bf[c][64+d] = bf16(cl[c]·Wv[:,d]).
__global__ __launch_bounds__(256) void pre(const float* __restrict__ cl,
                                           const float* __restrict__ Wk,
                                           const float* __restrict__ Wq,
                                           const float* __restrict__ Wv,
                                           short* __restrict__ Bf) {
  __shared__ float M1[64 * 64];
  const int t = threadIdx.x;
  const int idx = blockIdx.x * 256 + t;
  const int which = idx >> 14;  // block-uniform (16384/256 = 64)
  if (which == 0) {
    const float4* Wk4 = (const float4*)Wk;
    const float4* Wq4 = (const float4*)Wq;
    for (int i = 0; i < 16; ++i) {
      int e = i * 256 + t, m = e >> 6, k = e & 63;
      float acc = 0.f;
#pragma unroll
      for (int jq = 0; jq < 16; ++jq) {
        float4 wk = Wk4[m * 16 + jq], wq = Wq4[k * 16 + jq];
        acc += wk.x * wq.x + wk.y * wq.y + wk.z * wq.z + wk.w * wq.w;
      }
      M1[e] = 0.125f * acc;
    }
  }
  __syncthreads();
  const int cd = idx & (C * D - 1);
  const int c = cd >> 6, d = cd & 63;
  float acc = 0.f;
  if (which == 0) {
#pragma unroll
    for (int m = 0; m < 64; ++m) acc += cl[c * 64 + m] * M1[m * 64 + d];
    Bf[c * 128 + d] = f2bf(acc);
  } else {
#pragma unroll
    for (int m = 0; m < 64; ++m) acc += cl[c * 64 + m] * Wv[m * 64 + d];
    Bf[c * 128 + 64 + d] = f2bf(acc);
  }
}

// Row packing (per 16-row M-tile mt, row r = qr*4 + jr):
//   p = mt*4 + jr  (0..11), user g = p/3, sub = p%3, l = sub*4 + qr (valid l<10)
// => in C/D space (row = kb*4 + jj) user g = (mt*4+jj)/3 is COMPILE-TIME.
__global__ __launch_bounds__(256, 4) void filter_main(
    const int* __restrict__ items, const float* __restrict__ te,
    const float* __restrict__ ue_g, const float* __restrict__ ie_g,
    const float* __restrict__ wf_g, const short* __restrict__ Bf,
    const int* __restrict__ users, const int* __restrict__ pos_items,
    const int* __restrict__ neg_items, const float* __restrict__ a1p,
    const float* __restrict__ a2p, const float* __restrict__ a3p,
    float* __restrict__ out, int B) {
  __shared__ float2 s_red[G][12][4];  // [user][l (0..11)][wave] -> (S,T)
  const int tid = threadIdx.x, w = tid >> 6, lane = tid & 63;
  const int col16 = lane & 15, kb = lane >> 4;
  const int qr = col16 >> 2, jr = col16 & 3;  // A-load row decomposition
  const int b4 = blockIdx.x * G;
  const int BD = B * D;

  const int us0 = users[b4], us1 = users[b4 + 1];
  const int us2 = users[b4 + 2], us3 = users[b4 + 3];
  const int usw = (w == 0) ? us0 : ((w == 1) ? us1 : ((w == 2) ? us2 : us3));

  // early long-latency loads, consumed after the barrier
  const float uev = ue_g[usw * D + lane];
  const float posv = ie_g[pos_items[b4 + w] * D + lane];
  const float negv = ie_g[neg_items[b4 + w] * D + lane];
  float wfv[L];
#pragma unroll
  for (int l = 0; l < L; ++l) wfv[l] = wf_g[(usw * L + l) * D + lane];
  const float a1 = *a1p, a2 = *a2p, a3 = *a3p;

  const float4* te4 = (const float4*)te;
  const float4* ie4 = (const float4*)ie_g;
  const float4* ue4 = (const float4*)ue_g;

  // ---- A fragments: 3 short tiles (rows -> users via packing) + 1 ue tile
  bf16x8 a00, a01, a10, a11, a20, a21, au0 = {}, au1 = {};
#define LOAD_MT(AV0, AV1, MT)                                                  \
  {                                                                            \
    int p = (MT)*4 + jr;                                                       \
    int g = p / 3;                                                             \
    int l = (p - g * 3) * 4 + qr;                                              \
    int uu = (g == 0) ? us0 : ((g == 1) ? us1 : ((g == 2) ? us2 : us3));       \
    if (l < L) {                                                               \
      int it = items[uu * L + l];                                              \
      int tb = (uu * L + l) * 16 + kb * 2, ib = it * 16 + kb * 2,              \
          ub = uu * 16 + kb * 2;                                               \
      float4 x0 = add3(te4[tb], ie4[ib], ue4[ub]);                             \
      float4 x1 = add3(te4[tb + 1], ie4[ib + 1], ue4[ub + 1]);                 \
      float4 x2 = add3(te4[tb + 8], ie4[ib + 8], ue4[ub + 8]);                 \
      float4 x3 = add3(te4[tb + 9], ie4[ib + 9], ue4[ub + 9]);                 \
      AV0 = pack8(x0, x1);                                                     \
      AV1 = pack8(x2, x3);                                                     \
    } else {                                                                   \
      AV0 = bf16x8{};                                                          \
      AV1 = bf16x8{};                                                          \
    }                                                                          \
  }
  LOAD_MT(a00, a01, 0)
  LOAD_MT(a10, a11, 1)
  LOAD_MT(a20, a21, 2)
  if (col16 < G) {  // ue tile rows 0..3 = users 0..3, K = 64..127 (V half)
    int uu = (col16 == 0) ? us0 : ((col16 == 1) ? us1 : ((col16 == 2) ? us2 : us3));
    int ub = uu * 16 + kb * 2;
    au0 = pack8(ue4[ub], ue4[ub + 1]);
    au1 = pack8(ue4[ub + 8], ue4[ub + 9]);
  }

  // ---- per-nt GEMM + softmax accumulation (no max-sub; fp32-safe range)
  float Sa[3][4], Ta[3][4];
#pragma unroll
  for (int mt = 0; mt < 3; ++mt)
#pragma unroll
    for (int jj = 0; jj < 4; ++jj) { Sa[mt][jj] = 0.f; Ta[mt][jj] = 0.f; }

#pragma unroll
  for (int nt = 0; nt < 4; ++nt) {
    const bf16x8* bp = (const bf16x8*)(Bf + ((w * 4 + nt) * 16 + col16) * 128);
    bf16x8 b0 = bp[kb], b1 = bp[4 + kb], b2 = bp[8 + kb], b3 = bp[12 + kb];
    f32x4 z = {0.f, 0.f, 0.f, 0.f};
    f32x4 c0 = z, c1 = z, c2 = z, cu = z;
    c0 = __builtin_amdgcn_mfma_f32_16x16x32_bf16(a00, b0, c0, 0, 0, 0);
    c0 = __builtin_amdgcn_mfma_f32_16x16x32_bf16(a01, b1, c0, 0, 0, 0);
    c1 = __builtin_amdgcn_mfma_f32_16x16x32_bf16(a10, b0, c1, 0, 0, 0);
    c1 = __builtin_amdgcn_mfma_f32_16x16x32_bf16(a11, b1, c1, 0, 0, 0);
    c2 = __builtin_amdgcn_mfma_f32_16x16x32_bf16(a20, b0, c2, 0, 0, 0);
    c2 = __builtin_amdgcn_mfma_f32_16x16x32_bf16(a21, b1, c2, 0, 0, 0);
    cu = __builtin_amdgcn_mfma_f32_16x16x32_bf16(au0, b2, cu, 0, 0, 0);
    cu = __builtin_amdgcn_mfma_f32_16x16x32_bf16(au1, b3, cu, 0, 0, 0);
    // vu[g] lives at lanes 0..15 (kb=0), reg g; broadcast to matching col16
    float vu0 = __shfl(cu[0], col16, 64);
    float vu1 = __shfl(cu[1], col16, 64);
    float vu2 = __shfl(cu[2], col16, 64);
    float vu3 = __shfl(cu[3], col16, 64);
#pragma unroll
    for (int mt = 0; mt < 3; ++mt)
#pragma unroll
      for (int jj = 0; jj < 4; ++jj) {
        float sv = (mt == 0) ? c0[jj] : (mt == 1) ? c1[jj] : c2[jj];
        float e = __expf(sv);
        const int g = (mt * 4 + jj) / 3;  // compile-time
        float vu = (g == 0) ? vu0 : ((g == 1) ? vu1 : ((g == 2) ? vu2 : vu3));
        Sa[mt][jj] += e;
        Ta[mt][jj] += e * vu;
      }
  }

  // ---- reduce over col16 (xor 1,2,4,8), write per-wave stats
#pragma unroll
  for (int mt = 0; mt < 3; ++mt)
#pragma unroll
    for (int jj = 0; jj < 4; ++jj) {
      float S = Sa[mt][jj], T = Ta[mt][jj];
      S += __shfl_xor(S, 1, 64); T += __shfl_xor(T, 1, 64);
      S += __shfl_xor(S, 2, 64); T += __shfl_xor(T, 2, 64);
      S += __shfl_xor(S, 4, 64); T += __shfl_xor(T, 4, 64);
      S += __shfl_xor(S, 8, 64); T += __shfl_xor(T, 8, 64);
      if (col16 == 0) {
        const int g = (mt * 4 + jj) / 3, sub = (mt * 4 + jj) % 3;
        s_red[g][sub * 4 + kb][w] = make_float2(S, T);  // row l = sub*4+kb
      }
    }
  __syncthreads();

  // ---- wave w owns user w: combine waves, s_l = T/S, nu, store all outputs
  float nu = 0.f;
#pragma unroll
  for (int l = 0; l < L; ++l) {
    float2 p0 = s_red[w][l][0], p1 = s_red[w][l][1];
    float2 p2 = s_red[w][l][2], p3 = s_red[w][l][3];
    float S = (p0.x + p1.x) + (p2.x + p3.x);
    float T = (p0.y + p1.y) + (p2.y + p3.y);
    nu += (T / S) * wfv[l];
  }
  out[(b4 + w) * D + lane] = a3 * (a1 * uev + a2 * nu);
  out[BD + (b4 + w) * D + lane] = posv;
  out[2 * BD + (b4 + w) * D + lane] = negv;
}

extern "C" void kernel_launch(void* const* d_in, const int* in_sizes, int n_in,
                              void* d_out, int out_size, void* d_ws, size_t ws_size,
                              hipStream_t stream) {
  const int* items = (const int*)d_in[0];
  const float* time_embs = (const float*)d_in[1];
  const float* user_emb = (const float*)d_in[2];
  const float* item_emb = (const float*)d_in[3];
  const float* cluster = (const float*)d_in[4];
  const float* wf = (const float*)d_in[5];
  const float* Wq = (const float*)d_in[6];
  const float* Wk = (const float*)d_in[7];
  const float* Wv = (const float*)d_in[8];
  const int* users = (const int*)d_in[9];
  const int* pos = (const int*)d_in[10];
  const int* neg = (const int*)d_in[11];
  const float* a1 = (const float*)d_in[12];
  const float* a2 = (const float*)d_in[13];
  const float* a3 = (const float*)d_in[14];
  const int B = in_sizes[9];

  short* Bf = (short*)d_ws;  // [C][128] bf16
  hipLaunchKernelGGL(pre, dim3(2 * C * D / 256), dim3(256), 0, stream,
                     cluster, Wk, Wq, Wv, Bf);
  hipLaunchKernelGGL(filter_main, dim3(B / G), dim3(256), 0, stream,
                     items, time_embs, user_emb, item_emb, wf, Bf,
                     users, pos, neg, a1, a2, a3, (float*)d_out, B);
}

// Round 6
// 42.523 us; speedup vs baseline: 4.7448x; 1.1561x over previous
//
#include <hip/hip_runtime.h>

#define D 64
#define L 10
#define C 256
#define G 4
#define SW 68  // padded LDS row stride (floats); 272 B, 16B-aligned

typedef __attribute__((ext_vector_type(8))) short bf16x8;
typedef __attribute__((ext_vector_type(4))) float f32x4;

__device__ inline short f2bf(float f) {
  unsigned u = __float_as_uint(f);
  u = (u + 0x7FFFu + ((u >> 16) & 1u)) >> 16;
  return (short)u;
}
__device__ inline float4 add3(float4 a, float4 b, float4 c) {
  return make_float4(a.x + b.x + c.x, a.y + b.y + c.y, a.z + b.z + c.z, a.w + b.w + c.w);
}
__device__ inline bf16x8 pack8(float4 a, float4 b) {
  bf16x8 r;
  r[0] = f2bf(a.x); r[1] = f2bf(a.y); r[2] = f2bf(a.z); r[3] = f2bf(a.w);
  r[4] = f2bf(b.x); r[5] = f2bf(b.y); r[6] = f2bf(b.z); r[7] = f2bf(b.w);
  return r;
}

// One pre-kernel. Blocks 0..63: Bf[c][k] = bf16(cl[c]·M1[:,k]) with
// M1 = 0.125*Wk@Wq^T recomputed per-block in LDS. Blocks 64..127:
// Bf[c][64+d] = bf16(cl[c]·Wv[:,d]).
__global__ __launch_bounds__(256) void pre(const float* __restrict__ cl,
                                           const float* __restrict__ Wk,
                                           const float* __restrict__ Wq,
                                           const float* __restrict__ Wv,
                                           short* __restrict__ Bf) {
  __shared__ float M1[64 * 64];
  const int t = threadIdx.x;
  const int idx = blockIdx.x * 256 + t;
  const int which = idx >> 14;  // block-uniform
  if (which == 0) {
    const float4* Wk4 = (const float4*)Wk;
    const float4* Wq4 = (const float4*)Wq;
    for (int i = 0; i < 16; ++i) {
      int e = i * 256 + t, m = e >> 6, k = e & 63;
      float acc = 0.f;
#pragma unroll
      for (int jq = 0; jq < 16; ++jq) {
        float4 wk = Wk4[m * 16 + jq], wq = Wq4[k * 16 + jq];
        acc += wk.x * wq.x + wk.y * wq.y + wk.z * wq.z + wk.w * wq.w;
      }
      M1[e] = 0.125f * acc;
    }
  }
  __syncthreads();
  const int cd = idx & (C * D - 1);
  const int c = cd >> 6, d = cd & 63;
  float acc = 0.f;
  if (which == 0) {
#pragma unroll
    for (int m = 0; m < 64; ++m) acc += cl[c * 64 + m] * M1[m * 64 + d];
    Bf[c * 128 + d] = f2bf(acc);
  } else {
#pragma unroll
    for (int m = 0; m < 64; ++m) acc += cl[c * 64 + m] * Wv[m * 64 + d];
    Bf[c * 128 + 64 + d] = f2bf(acc);
  }
}

// Row packing (verified R4/R5): A-tile row r=(qr*4+jr); p=mt*4+jr, g=p/3,
// sub=p%3, l=sub*4+qr (valid l<10). In C/D space (row=kb*4+jj): p=mt*4+jj,
// l=sub*4+kb -> user g compile-time per (mt,jj).
__global__ __launch_bounds__(256, 4) void filter_main(
    const int* __restrict__ items, const float* __restrict__ te,
    const float* __restrict__ ue_g, const float* __restrict__ ie_g,
    const float* __restrict__ wf_g, const short* __restrict__ Bf,
    const int* __restrict__ users, const int* __restrict__ pos_items,
    const int* __restrict__ neg_items, const float* __restrict__ a1p,
    const float* __restrict__ a2p, const float* __restrict__ a3p,
    float* __restrict__ out, int B) {
  __shared__ float s_sh[40 * SW];    // short rows (fp32), padded stride
  __shared__ float s_ue[G * SW];     // user embeddings, padded stride
  __shared__ int s_items[G * 12];
  __shared__ float2 s_red[G][12][4];

  const int tid = threadIdx.x, w = tid >> 6, lane = tid & 63;
  const int col16 = lane & 15, kb = lane >> 4;
  const int qr = col16 >> 2, jr = col16 & 3;
  const int b4 = blockIdx.x * G;
  const int BD = B * D;

  const int us0 = users[b4], us1 = users[b4 + 1];
  const int us2 = users[b4 + 2], us3 = users[b4 + 3];
  const int usw = (w == 0) ? us0 : ((w == 1) ? us1 : ((w == 2) ? us2 : us3));

  // early long-latency, coalesced per-row loads (consumed at the end)
  const float uev = ue_g[usw * D + lane];
  const float posv = ie_g[pos_items[b4 + w] * D + lane];
  const float negv = ie_g[neg_items[b4 + w] * D + lane];
  float wfv[L];
#pragma unroll
  for (int l = 0; l < L; ++l) wfv[l] = wf_g[(usw * L + l) * D + lane];
  const float a1 = *a1p, a2 = *a2p, a3 = *a3p;

  if (lane < L) s_items[w * 12 + lane] = items[usw * L + lane];
  s_ue[w * SW + lane] = uev;
  __syncthreads();

  // ---- coalesced staging: short[row] = te + ie + ue, 16 lanes per row
  {
    const float4* te4 = (const float4*)te;
    const float4* ie4 = (const float4*)ie_g;
    const int grp = tid >> 4, j = tid & 15;
#pragma unroll
    for (int it = 0; it < 3; ++it) {
      int row = it * 16 + grp;
      if (row < 40) {
        int g = row / 10, l = row - g * 10;
        int uu = (g == 0) ? us0 : ((g == 1) ? us1 : ((g == 2) ? us2 : us3));
        int itm = s_items[g * 12 + l];
        float4 t = te4[(uu * L + l) * 16 + j];
        float4 e = ie4[itm * 16 + j];
        float4 uef = *(const float4*)&s_ue[g * SW + j * 4];
        *(float4*)&s_sh[row * SW + j * 4] = add3(t, e, uef);
      }
    }
  }
  __syncthreads();

  // ---- A fragments from LDS
  bf16x8 a00, a01, a10, a11, a20, a21, au0 = {}, au1 = {};
#define FRAG(AV0, AV1, MT)                                                     \
  {                                                                            \
    int p = (MT)*4 + jr;                                                       \
    int g = p / 3;                                                             \
    int l = (p - g * 3) * 4 + qr;                                              \
    if (l < L) {                                                               \
      const float4* r = (const float4*)&s_sh[(g * 10 + l) * SW];               \
      AV0 = pack8(r[kb * 2], r[kb * 2 + 1]);                                   \
      AV1 = pack8(r[kb * 2 + 8], r[kb * 2 + 9]);                               \
    } else {                                                                   \
      AV0 = bf16x8{};                                                          \
      AV1 = bf16x8{};                                                          \
    }                                                                          \
  }
  FRAG(a00, a01, 0)
  FRAG(a10, a11, 1)
  FRAG(a20, a21, 2)
  if (col16 < G) {
    const float4* r = (const float4*)&s_ue[col16 * SW];
    au0 = pack8(r[kb * 2], r[kb * 2 + 1]);
    au1 = pack8(r[kb * 2 + 8], r[kb * 2 + 9]);
  }

  // ---- per-nt GEMM + softmax accumulation (no max-sub; fp32-safe range)
  float Sa[3][4], Ta[3][4];
#pragma unroll
  for (int mt = 0; mt < 3; ++mt)
#pragma unroll
    for (int jj = 0; jj < 4; ++jj) { Sa[mt][jj] = 0.f; Ta[mt][jj] = 0.f; }

#pragma unroll
  for (int nt = 0; nt < 4; ++nt) {
    const bf16x8* bp = (const bf16x8*)(Bf + ((w * 4 + nt) * 16 + col16) * 128);
    bf16x8 b0 = bp[kb], b1 = bp[4 + kb], b2 = bp[8 + kb], b3 = bp[12 + kb];
    f32x4 z = {0.f, 0.f, 0.f, 0.f};
    f32x4 c0 = z, c1 = z, c2 = z, cu = z;
    c0 = __builtin_amdgcn_mfma_f32_16x16x32_bf16(a00, b0, c0, 0, 0, 0);
    c0 = __builtin_amdgcn_mfma_f32_16x16x32_bf16(a01, b1, c0, 0, 0, 0);
    c1 = __builtin_amdgcn_mfma_f32_16x16x32_bf16(a10, b0, c1, 0, 0, 0);
    c1 = __builtin_amdgcn_mfma_f32_16x16x32_bf16(a11, b1, c1, 0, 0, 0);
    c2 = __builtin_amdgcn_mfma_f32_16x16x32_bf16(a20, b0, c2, 0, 0, 0);
    c2 = __builtin_amdgcn_mfma_f32_16x16x32_bf16(a21, b1, c2, 0, 0, 0);
    cu = __builtin_amdgcn_mfma_f32_16x16x32_bf16(au0, b2, cu, 0, 0, 0);
    cu = __builtin_amdgcn_mfma_f32_16x16x32_bf16(au1, b3, cu, 0, 0, 0);
    float vu0 = __shfl(cu[0], col16, 64);
    float vu1 = __shfl(cu[1], col16, 64);
    float vu2 = __shfl(cu[2], col16, 64);
    float vu3 = __shfl(cu[3], col16, 64);
#pragma unroll
    for (int mt = 0; mt < 3; ++mt)
#pragma unroll
      for (int jj = 0; jj < 4; ++jj) {
        float sv = (mt == 0) ? c0[jj] : (mt == 1) ? c1[jj] : c2[jj];
        float e = __expf(sv);
        const int g = (mt * 4 + jj) / 3;  // compile-time
        float vu = (g == 0) ? vu0 : ((g == 1) ? vu1 : ((g == 2) ? vu2 : vu3));
        Sa[mt][jj] += e;
        Ta[mt][jj] += e * vu;
      }
  }

  // ---- reduce over col16, write per-wave stats
#pragma unroll
  for (int mt = 0; mt < 3; ++mt)
#pragma unroll
    for (int jj = 0; jj < 4; ++jj) {
      float S = Sa[mt][jj], T = Ta[mt][jj];
      S += __shfl_xor(S, 1, 64); T += __shfl_xor(T, 1, 64);
      S += __shfl_xor(S, 2, 64); T += __shfl_xor(T, 2, 64);
      S += __shfl_xor(S, 4, 64); T += __shfl_xor(T, 4, 64);
      S += __shfl_xor(S, 8, 64); T += __shfl_xor(T, 8, 64);
      if (col16 == 0) {
        const int g = (mt * 4 + jj) / 3, sub = (mt * 4 + jj) % 3;
        s_red[g][sub * 4 + kb][w] = make_float2(S, T);
      }
    }
  __syncthreads();

  // ---- wave w owns user w: combine waves, s_l = T/S, nu, store outputs
  float nu = 0.f;
#pragma unroll
  for (int l = 0; l < L; ++l) {
    float2 p0 = s_red[w][l][0], p1 = s_red[w][l][1];
    float2 p2 = s_red[w][l][2], p3 = s_red[w][l][3];
    float S = (p0.x + p1.x) + (p2.x + p3.x);
    float T = (p0.y + p1.y) + (p2.y + p3.y);
    nu += T * __frcp_rn(S) * wfv[l];
  }
  out[(b4 + w) * D + lane] = a3 * (a1 * uev + a2 * nu);
  out[BD + (b4 + w) * D + lane] = posv;
  out[2 * BD + (b4 + w) * D + lane] = negv;
}

extern "C" void kernel_launch(void* const* d_in, const int* in_sizes, int n_in,
                              void* d_out, int out_size, void* d_ws, size_t ws_size,
                              hipStream_t stream) {
  const int* items = (const int*)d_in[0];
  const float* time_embs = (const float*)d_in[1];
  const float* user_emb = (const float*)d_in[2];
  const float* item_emb = (const float*)d_in[3];
  const float* cluster = (const float*)d_in[4];
  const float* wf = (const float*)d_in[5];
  const float* Wq = (const float*)d_in[6];
  const float* Wk = (const float*)d_in[7];
  const float* Wv = (const float*)d_in[8];
  const int* users = (const int*)d_in[9];
  const int* pos = (const int*)d_in[10];
  const int* neg = (const int*)d_in[11];
  const float* a1 = (const float*)d_in[12];
  const float* a2 = (const float*)d_in[13];
  const float* a3 = (const float*)d_in[14];
  const int B = in_sizes[9];

  short* Bf = (short*)d_ws;  // [C][128] bf16
  hipLaunchKernelGGL(pre, dim3(2 * C * D / 256), dim3(256), 0, stream,
                     cluster, Wk, Wq, Wv, Bf);
  hipLaunchKernelGGL(filter_main, dim3(B / G), dim3(256), 0, stream,
                     items, time_embs, user_emb, item_emb, wf, Bf,
                     users, pos, neg, a1, a2, a3, (float*)d_out, B);
}

// Round 7
// 41.854 us; speedup vs baseline: 4.8206x; 1.0160x over previous
//
#include <hip/hip_runtime.h>

#define D 64
#define L 10
#define C 256
#define G 4
#define SWB 72  // bf16 LDS row stride in shorts (144 B, 16B-aligned)

typedef __attribute__((ext_vector_type(8))) short bf16x8;
typedef __attribute__((ext_vector_type(4))) short short4v;
typedef __attribute__((ext_vector_type(4))) float f32x4;

__device__ inline short f2bf(float f) {
  unsigned u = __float_as_uint(f);
  u = (u + 0x7FFFu + ((u >> 16) & 1u)) >> 16;
  return (short)u;
}
__device__ inline float4 add3(float4 a, float4 b, float4 c) {
  return make_float4(a.x + b.x + c.x, a.y + b.y + c.y, a.z + b.z + c.z, a.w + b.w + c.w);
}
__device__ inline short4v f2bf4(float4 a) {
  short4v r;
  r[0] = f2bf(a.x); r[1] = f2bf(a.y); r[2] = f2bf(a.z); r[3] = f2bf(a.w);
  return r;
}

// One pre-kernel. Blocks 0..63: Bf[c][k] = bf16(cl[c]·M1[:,k]) with
// M1 = 0.125*Wk@Wq^T recomputed per-block in LDS. Blocks 64..127:
// Bf[c][64+d] = bf16(cl[c]·Wv[:,d]).
__global__ __launch_bounds__(256) void pre(const float* __restrict__ cl,
                                           const float* __restrict__ Wk,
                                           const float* __restrict__ Wq,
                                           const float* __restrict__ Wv,
                                           short* __restrict__ Bf) {
  __shared__ float M1[64 * 64];
  const int t = threadIdx.x;
  const int idx = blockIdx.x * 256 + t;
  const int which = idx >> 14;  // block-uniform
  if (which == 0) {
    const float4* Wk4 = (const float4*)Wk;
    const float4* Wq4 = (const float4*)Wq;
    for (int i = 0; i < 16; ++i) {
      int e = i * 256 + t, m = e >> 6, k = e & 63;
      float acc = 0.f;
#pragma unroll
      for (int jq = 0; jq < 16; ++jq) {
        float4 wk = Wk4[m * 16 + jq], wq = Wq4[k * 16 + jq];
        acc += wk.x * wq.x + wk.y * wq.y + wk.z * wq.z + wk.w * wq.w;
      }
      M1[e] = 0.125f * acc;
    }
  }
  __syncthreads();
  const int cd = idx & (C * D - 1);
  const int c = cd >> 6, d = cd & 63;
  float acc = 0.f;
  if (which == 0) {
#pragma unroll
    for (int m = 0; m < 64; ++m) acc += cl[c * 64 + m] * M1[m * 64 + d];
    Bf[c * 128 + d] = f2bf(acc);
  } else {
#pragma unroll
    for (int m = 0; m < 64; ++m) acc += cl[c * 64 + m] * Wv[m * 64 + d];
    Bf[c * 128 + 64 + d] = f2bf(acc);
  }
}

// Row packing (verified R4-R6): A-tile row r=(qr*4+jr); p=mt*4+jr, g=p/3,
// sub=p%3, l=sub*4+qr (valid l<10). In C/D space (row=kb*4+jj): p=mt*4+jj,
// l=sub*4+kb -> user g compile-time per (mt,jj).
__global__ __launch_bounds__(256, 4) void filter_main(
    const int* __restrict__ items, const float* __restrict__ te,
    const float* __restrict__ ue_g, const float* __restrict__ ie_g,
    const float* __restrict__ wf_g, const short* __restrict__ Bf,
    const int* __restrict__ users, const int* __restrict__ pos_items,
    const int* __restrict__ neg_items, const float* __restrict__ a1p,
    const float* __restrict__ a2p, const float* __restrict__ a3p,
    float* __restrict__ out, int B) {
  __shared__ short s_shb[40 * SWB];   // short rows, bf16
  __shared__ short s_ueb[G * SWB];    // ue rows, bf16
  __shared__ float2 s_red[G][12][4];

  const int tid = threadIdx.x, w = tid >> 6, lane = tid & 63;
  const int col16 = lane & 15, kb = lane >> 4;
  const int qr = col16 >> 2, jr = col16 & 3;
  const int b4 = blockIdx.x * G;
  const int BD = B * D;

  const int us0 = users[b4], us1 = users[b4 + 1];
  const int us2 = users[b4 + 2], us3 = users[b4 + 3];
  const int usw = (w == 0) ? us0 : ((w == 1) ? us1 : ((w == 2) ? us2 : us3));

  // early long-latency, coalesced per-row loads (consumed at the end)
  const float uev = ue_g[usw * D + lane];
  const float posv = ie_g[pos_items[b4 + w] * D + lane];
  const float negv = ie_g[neg_items[b4 + w] * D + lane];
  float wfv[L];
#pragma unroll
  for (int l = 0; l < L; ++l) wfv[l] = wf_g[(usw * L + l) * D + lane];
  const float a1 = *a1p, a2 = *a2p, a3 = *a3p;

  // ue rows as bf16 (for the V-half A-tile)
  s_ueb[w * SWB + lane] = f2bf(uev);

  // ---- coalesced staging: short[row] = te + ie + ue -> bf16 LDS
  {
    const float4* te4 = (const float4*)te;
    const float4* ie4 = (const float4*)ie_g;
    const float4* ue4 = (const float4*)ue_g;
    const int grp = tid >> 4, j = tid & 15;
#pragma unroll
    for (int it = 0; it < 3; ++it) {
      int row = it * 16 + grp;
      if (row < 40) {
        int g = row / 10, l = row - g * 10;
        int uu = (g == 0) ? us0 : ((g == 1) ? us1 : ((g == 2) ? us2 : us3));
        int itm = items[uu * L + l];
        float4 t = te4[(uu * L + l) * 16 + j];
        float4 e = ie4[itm * 16 + j];
        float4 uf = ue4[uu * 16 + j];
        *(short4v*)&s_shb[row * SWB + j * 4] = f2bf4(add3(t, e, uf));
      }
    }
  }
  __syncthreads();

  // ---- A fragments: pure ds_read_b128 from bf16 LDS
  bf16x8 a00, a01, a10, a11, a20, a21, au0 = {}, au1 = {};
#define FRAG(AV0, AV1, MT)                                                     \
  {                                                                            \
    int p = (MT)*4 + jr;                                                       \
    int g = p / 3;                                                             \
    int l = (p - g * 3) * 4 + qr;                                              \
    if (l < L) {                                                               \
      const bf16x8* rp = (const bf16x8*)&s_shb[(g * 10 + l) * SWB];            \
      AV0 = rp[kb];                                                            \
      AV1 = rp[4 + kb];                                                        \
    } else {                                                                   \
      AV0 = bf16x8{};                                                          \
      AV1 = bf16x8{};                                                          \
    }                                                                          \
  }
  FRAG(a00, a01, 0)
  FRAG(a10, a11, 1)
  FRAG(a20, a21, 2)
  if (col16 < G) {
    const bf16x8* rp = (const bf16x8*)&s_ueb[col16 * SWB];
    au0 = rp[kb];
    au1 = rp[4 + kb];
  }

  // ---- per-nt GEMM + softmax accumulation (no max-sub; fp32-safe range)
  float Sa[3][4], Ta[3][4];
#pragma unroll
  for (int mt = 0; mt < 3; ++mt)
#pragma unroll
    for (int jj = 0; jj < 4; ++jj) { Sa[mt][jj] = 0.f; Ta[mt][jj] = 0.f; }

#pragma unroll
  for (int nt = 0; nt < 4; ++nt) {
    const bf16x8* bp = (const bf16x8*)(Bf + ((w * 4 + nt) * 16 + col16) * 128);
    bf16x8 b0 = bp[kb], b1 = bp[4 + kb], b2 = bp[8 + kb], b3 = bp[12 + kb];
    f32x4 z = {0.f, 0.f, 0.f, 0.f};
    f32x4 c0 = z, c1 = z, c2 = z, cu = z;
    c0 = __builtin_amdgcn_mfma_f32_16x16x32_bf16(a00, b0, c0, 0, 0, 0);
    c0 = __builtin_amdgcn_mfma_f32_16x16x32_bf16(a01, b1, c0, 0, 0, 0);
    c1 = __builtin_amdgcn_mfma_f32_16x16x32_bf16(a10, b0, c1, 0, 0, 0);
    c1 = __builtin_amdgcn_mfma_f32_16x16x32_bf16(a11, b1, c1, 0, 0, 0);
    c2 = __builtin_amdgcn_mfma_f32_16x16x32_bf16(a20, b0, c2, 0, 0, 0);
    c2 = __builtin_amdgcn_mfma_f32_16x16x32_bf16(a21, b1, c2, 0, 0, 0);
    cu = __builtin_amdgcn_mfma_f32_16x16x32_bf16(au0, b2, cu, 0, 0, 0);
    cu = __builtin_amdgcn_mfma_f32_16x16x32_bf16(au1, b3, cu, 0, 0, 0);
    float vu0 = __shfl(cu[0], col16, 64);
    float vu1 = __shfl(cu[1], col16, 64);
    float vu2 = __shfl(cu[2], col16, 64);
    float vu3 = __shfl(cu[3], col16, 64);
#pragma unroll
    for (int mt = 0; mt < 3; ++mt)
#pragma unroll
      for (int jj = 0; jj < 4; ++jj) {
        float sv = (mt == 0) ? c0[jj] : (mt == 1) ? c1[jj] : c2[jj];
        float e = __expf(sv);
        const int g = (mt * 4 + jj) / 3;  // compile-time
        float vu = (g == 0) ? vu0 : ((g == 1) ? vu1 : ((g == 2) ? vu2 : vu3));
        Sa[mt][jj] += e;
        Ta[mt][jj] += e * vu;
      }
  }

  // ---- reduce over col16, write per-wave stats
#pragma unroll
  for (int mt = 0; mt < 3; ++mt)
#pragma unroll
    for (int jj = 0; jj < 4; ++jj) {
      float S = Sa[mt][jj], T = Ta[mt][jj];
      S += __shfl_xor(S, 1, 64); T += __shfl_xor(T, 1, 64);
      S += __shfl_xor(S, 2, 64); T += __shfl_xor(T, 2, 64);
      S += __shfl_xor(S, 4, 64); T += __shfl_xor(T, 4, 64);
      S += __shfl_xor(S, 8, 64); T += __shfl_xor(T, 8, 64);
      if (col16 == 0) {
        const int g = (mt * 4 + jj) / 3, sub = (mt * 4 + jj) % 3;
        s_red[g][sub * 4 + kb][w] = make_float2(S, T);
      }
    }
  __syncthreads();

  // ---- wave w owns user w: combine waves, s_l = T/S, nu, store outputs
  float nu = 0.f;
#pragma unroll
  for (int l = 0; l < L; ++l) {
    float2 p0 = s_red[w][l][0], p1 = s_red[w][l][1];
    float2 p2 = s_red[w][l][2], p3 = s_red[w][l][3];
    float S = (p0.x + p1.x) + (p2.x + p3.x);
    float T = (p0.y + p1.y) + (p2.y + p3.y);
    nu += T * __frcp_rn(S) * wfv[l];
  }
  out[(b4 + w) * D + lane] = a3 * (a1 * uev + a2 * nu);
  out[BD + (b4 + w) * D + lane] = posv;
  out[2 * BD + (b4 + w) * D + lane] = negv;
}

extern "C" void kernel_launch(void* const* d_in, const int* in_sizes, int n_in,
                              void* d_out, int out_size, void* d_ws, size_t ws_size,
                              hipStream_t stream) {
  const int* items = (const int*)d_in[0];
  const float* time_embs = (const float*)d_in[1];
  const float* user_emb = (const float*)d_in[2];
  const float* item_emb = (const float*)d_in[3];
  const float* cluster = (const float*)d_in[4];
  const float* wf = (const float*)d_in[5];
  const float* Wq = (const float*)d_in[6];
  const float* Wk = (const float*)d_in[7];
  const float* Wv = (const float*)d_in[8];
  const int* users = (const int*)d_in[9];
  const int* pos = (const int*)d_in[10];
  const int* neg = (const int*)d_in[11];
  const float* a1 = (const float*)d_in[12];
  const float* a2 = (const float*)d_in[13];
  const float* a3 = (const float*)d_in[14];
  const int B = in_sizes[9];

  short* Bf = (short*)d_ws;  // [C][128] bf16
  hipLaunchKernelGGL(pre, dim3(2 * C * D / 256), dim3(256), 0, stream,
                     cluster, Wk, Wq, Wv, Bf);
  hipLaunchKernelGGL(filter_main, dim3(B / G), dim3(256), 0, stream,
                     items, time_embs, user_emb, item_emb, wf, Bf,
                     users, pos, neg, a1, a2, a3, (float*)d_out, B);
}

// Round 8
// 28.998 us; speedup vs baseline: 6.9578x; 1.4433x over previous
//
#include <hip/hip_runtime.h>

#define D 64
#define L 10
#define C 256
#define G 4
#define SWB 72  // bf16 LDS row stride in shorts (144 B, 16B-aligned)

typedef __attribute__((ext_vector_type(8))) short bf16x8;
typedef __attribute__((ext_vector_type(4))) short short4v;
typedef __attribute__((ext_vector_type(4))) float f32x4;

__device__ inline short f2bf(float f) {
  unsigned u = __float_as_uint(f);
  u = (u + 0x7FFFu + ((u >> 16) & 1u)) >> 16;
  return (short)u;
}
__device__ inline float4 add3(float4 a, float4 b, float4 c) {
  return make_float4(a.x + b.x + c.x, a.y + b.y + c.y, a.z + b.z + c.z, a.w + b.w + c.w);
}
__device__ inline short4v f2bf4(float4 a) {
  short4v r;
  r[0] = f2bf(a.x); r[1] = f2bf(a.y); r[2] = f2bf(a.z); r[3] = f2bf(a.w);
  return r;
}

// Coalesced pre. 128 blocks x 256 threads; block bh = blk>>6 (0: WqK half,
// 1: V half), cb = blk&63 -> 4 c-rows. All global reads coalesced; Wq held
// in LDS with +1-row padding (stride 65) so the final row-dot is conflict-free.
// Bf[c][k]    = bf16( 0.125 * (cl@Wk)[c] . Wq[k] )   (== 0.125*(cl@Wk@Wq^T))
// Bf[c][64+d] = bf16( (cl@Wv)[c][d] )
__global__ __launch_bounds__(256) void pre(const float* __restrict__ cl,
                                           const float* __restrict__ Wk,
                                           const float* __restrict__ Wq,
                                           const float* __restrict__ Wv,
                                           short* __restrict__ Bf) {
  __shared__ float s_cl[4 * 64];   // 4 cluster rows
  __shared__ float s_kc[4 * 64];   // 4 rows of cl@Wk
  __shared__ float s_w[64 * 65];   // Wq rows, padded stride 65
  const int t = threadIdx.x;
  const int bh = blockIdx.x >> 6, cb = blockIdx.x & 63;
  const int c0 = cb * 4;
  const int r = t >> 6, j = t & 63;

  s_cl[t] = cl[c0 * 64 + t];  // coalesced
  if (bh == 0) {
#pragma unroll
    for (int i = 0; i < 4; ++i) {  // stage Wq (1024 float4, coalesced reads)
      int e = i * 256 + t;
      float4 v = ((const float4*)Wq)[e];
      int k = e >> 4, q = e & 15;
      float* dst = &s_w[k * 65 + q * 4];
      dst[0] = v.x; dst[1] = v.y; dst[2] = v.z; dst[3] = v.w;
    }
  }
  __syncthreads();

  const float* __restrict__ Wx = bh ? Wv : Wk;
  float acc = 0.f;
#pragma unroll 8
  for (int m = 0; m < 64; ++m) acc += s_cl[r * 64 + m] * Wx[m * 64 + j];

  if (bh == 1) {  // V half: direct store (block-uniform branch)
    Bf[(c0 + r) * 128 + 64 + j] = f2bf(acc);
    return;
  }
  s_kc[t] = acc;
  __syncthreads();

  float o = 0.f;
#pragma unroll 8
  for (int jj = 0; jj < 64; ++jj) o += s_kc[r * 64 + jj] * s_w[j * 65 + jj];
  Bf[(c0 + r) * 128 + j] = f2bf(0.125f * o);
}

// Row packing (verified R4-R7): A-tile row r=(qr*4+jr); p=mt*4+jr, g=p/3,
// sub=p%3, l=sub*4+qr (valid l<10). In C/D space (row=kb*4+jj): p=mt*4+jj,
// l=sub*4+kb -> user g compile-time per (mt,jj).
__global__ __launch_bounds__(256, 4) void filter_main(
    const int* __restrict__ items, const float* __restrict__ te,
    const float* __restrict__ ue_g, const float* __restrict__ ie_g,
    const float* __restrict__ wf_g, const short* __restrict__ Bf,
    const int* __restrict__ users, const int* __restrict__ pos_items,
    const int* __restrict__ neg_items, const float* __restrict__ a1p,
    const float* __restrict__ a2p, const float* __restrict__ a3p,
    float* __restrict__ out, int B) {
  __shared__ short s_shb[40 * SWB];   // short rows, bf16
  __shared__ short s_ueb[G * SWB];    // ue rows, bf16
  __shared__ float2 s_red[G][12][4];

  const int tid = threadIdx.x, w = tid >> 6, lane = tid & 63;
  const int col16 = lane & 15, kb = lane >> 4;
  const int qr = col16 >> 2, jr = col16 & 3;
  const int b4 = blockIdx.x * G;
  const int BD = B * D;

  const int us0 = users[b4], us1 = users[b4 + 1];
  const int us2 = users[b4 + 2], us3 = users[b4 + 3];
  const int usw = (w == 0) ? us0 : ((w == 1) ? us1 : ((w == 2) ? us2 : us3));

  // early long-latency, coalesced per-row loads (consumed at the end)
  const float uev = ue_g[usw * D + lane];
  const float posv = ie_g[pos_items[b4 + w] * D + lane];
  const float negv = ie_g[neg_items[b4 + w] * D + lane];
  float wfv[L];
#pragma unroll
  for (int l = 0; l < L; ++l) wfv[l] = wf_g[(usw * L + l) * D + lane];
  const float a1 = *a1p, a2 = *a2p, a3 = *a3p;

  // ue rows as bf16 (for the V-half A-tile)
  s_ueb[w * SWB + lane] = f2bf(uev);

  // ---- coalesced staging: short[row] = te + ie + ue -> bf16 LDS
  {
    const float4* te4 = (const float4*)te;
    const float4* ie4 = (const float4*)ie_g;
    const float4* ue4 = (const float4*)ue_g;
    const int grp = tid >> 4, j = tid & 15;
#pragma unroll
    for (int it = 0; it < 3; ++it) {
      int row = it * 16 + grp;
      if (row < 40) {
        int g = row / 10, l = row - g * 10;
        int uu = (g == 0) ? us0 : ((g == 1) ? us1 : ((g == 2) ? us2 : us3));
        int itm = items[uu * L + l];
        float4 t = te4[(uu * L + l) * 16 + j];
        float4 e = ie4[itm * 16 + j];
        float4 uf = ue4[uu * 16 + j];
        *(short4v*)&s_shb[row * SWB + j * 4] = f2bf4(add3(t, e, uf));
      }
    }
  }
  __syncthreads();

  // ---- A fragments: pure ds_read_b128 from bf16 LDS
  bf16x8 a00, a01, a10, a11, a20, a21, au0 = {}, au1 = {};
#define FRAG(AV0, AV1, MT)                                                     \
  {                                                                            \
    int p = (MT)*4 + jr;                                                       \
    int g = p / 3;                                                             \
    int l = (p - g * 3) * 4 + qr;                                              \
    if (l < L) {                                                               \
      const bf16x8* rp = (const bf16x8*)&s_shb[(g * 10 + l) * SWB];            \
      AV0 = rp[kb];                                                            \
      AV1 = rp[4 + kb];                                                        \
    } else {                                                                   \
      AV0 = bf16x8{};                                                          \
      AV1 = bf16x8{};                                                          \
    }                                                                          \
  }
  FRAG(a00, a01, 0)
  FRAG(a10, a11, 1)
  FRAG(a20, a21, 2)
  if (col16 < G) {
    const bf16x8* rp = (const bf16x8*)&s_ueb[col16 * SWB];
    au0 = rp[kb];
    au1 = rp[4 + kb];
  }

  // ---- per-nt GEMM + softmax accumulation (no max-sub; fp32-safe range)
  float Sa[3][4], Ta[3][4];
#pragma unroll
  for (int mt = 0; mt < 3; ++mt)
#pragma unroll
    for (int jj = 0; jj < 4; ++jj) { Sa[mt][jj] = 0.f; Ta[mt][jj] = 0.f; }

#pragma unroll
  for (int nt = 0; nt < 4; ++nt) {
    const bf16x8* bp = (const bf16x8*)(Bf + ((w * 4 + nt) * 16 + col16) * 128);
    bf16x8 b0 = bp[kb], b1 = bp[4 + kb], b2 = bp[8 + kb], b3 = bp[12 + kb];
    f32x4 z = {0.f, 0.f, 0.f, 0.f};
    f32x4 c0 = z, c1 = z, c2 = z, cu = z;
    c0 = __builtin_amdgcn_mfma_f32_16x16x32_bf16(a00, b0, c0, 0, 0, 0);
    c0 = __builtin_amdgcn_mfma_f32_16x16x32_bf16(a01, b1, c0, 0, 0, 0);
    c1 = __builtin_amdgcn_mfma_f32_16x16x32_bf16(a10, b0, c1, 0, 0, 0);
    c1 = __builtin_amdgcn_mfma_f32_16x16x32_bf16(a11, b1, c1, 0, 0, 0);
    c2 = __builtin_amdgcn_mfma_f32_16x16x32_bf16(a20, b0, c2, 0, 0, 0);
    c2 = __builtin_amdgcn_mfma_f32_16x16x32_bf16(a21, b1, c2, 0, 0, 0);
    cu = __builtin_amdgcn_mfma_f32_16x16x32_bf16(au0, b2, cu, 0, 0, 0);
    cu = __builtin_amdgcn_mfma_f32_16x16x32_bf16(au1, b3, cu, 0, 0, 0);
    float vu0 = __shfl(cu[0], col16, 64);
    float vu1 = __shfl(cu[1], col16, 64);
    float vu2 = __shfl(cu[2], col16, 64);
    float vu3 = __shfl(cu[3], col16, 64);
#pragma unroll
    for (int mt = 0; mt < 3; ++mt)
#pragma unroll
      for (int jj = 0; jj < 4; ++jj) {
        float sv = (mt == 0) ? c0[jj] : (mt == 1) ? c1[jj] : c2[jj];
        float e = __expf(sv);
        const int g = (mt * 4 + jj) / 3;  // compile-time
        float vu = (g == 0) ? vu0 : ((g == 1) ? vu1 : ((g == 2) ? vu2 : vu3));
        Sa[mt][jj] += e;
        Ta[mt][jj] += e * vu;
      }
  }

  // ---- reduce over col16, write per-wave stats
#pragma unroll
  for (int mt = 0; mt < 3; ++mt)
#pragma unroll
    for (int jj = 0; jj < 4; ++jj) {
      float S = Sa[mt][jj], T = Ta[mt][jj];
      S += __shfl_xor(S, 1, 64); T += __shfl_xor(T, 1, 64);
      S += __shfl_xor(S, 2, 64); T += __shfl_xor(T, 2, 64);
      S += __shfl_xor(S, 4, 64); T += __shfl_xor(T, 4, 64);
      S += __shfl_xor(S, 8, 64); T += __shfl_xor(T, 8, 64);
      if (col16 == 0) {
        const int g = (mt * 4 + jj) / 3, sub = (mt * 4 + jj) % 3;
        s_red[g][sub * 4 + kb][w] = make_float2(S, T);
      }
    }
  __syncthreads();

  // ---- wave w owns user w: combine waves, s_l = T/S, nu, store outputs
  float nu = 0.f;
#pragma unroll
  for (int l = 0; l < L; ++l) {
    float2 p0 = s_red[w][l][0], p1 = s_red[w][l][1];
    float2 p2 = s_red[w][l][2], p3 = s_red[w][l][3];
    float S = (p0.x + p1.x) + (p2.x + p3.x);
    float T = (p0.y + p1.y) + (p2.y + p3.y);
    nu += T * __frcp_rn(S) * wfv[l];
  }
  out[(b4 + w) * D + lane] = a3 * (a1 * uev + a2 * nu);
  out[BD + (b4 + w) * D + lane] = posv;
  out[2 * BD + (b4 + w) * D + lane] = negv;
}

extern "C" void kernel_launch(void* const* d_in, const int* in_sizes, int n_in,
                              void* d_out, int out_size, void* d_ws, size_t ws_size,
                              hipStream_t stream) {
  const int* items = (const int*)d_in[0];
  const float* time_embs = (const float*)d_in[1];
  const float* user_emb = (const float*)d_in[2];
  const float* item_emb = (const float*)d_in[3];
  const float* cluster = (const float*)d_in[4];
  const float* wf = (const float*)d_in[5];
  const float* Wq = (const float*)d_in[6];
  const float* Wk = (const float*)d_in[7];
  const float* Wv = (const float*)d_in[8];
  const int* users = (const int*)d_in[9];
  const int* pos = (const int*)d_in[10];
  const int* neg = (const int*)d_in[11];
  const float* a1 = (const float*)d_in[12];
  const float* a2 = (const float*)d_in[13];
  const float* a3 = (const float*)d_in[14];
  const int B = in_sizes[9];

  short* Bf = (short*)d_ws;  // [C][128] bf16
  hipLaunchKernelGGL(pre, dim3(128), dim3(256), 0, stream,
                     cluster, Wk, Wq, Wv, Bf);
  hipLaunchKernelGGL(filter_main, dim3(B / G), dim3(256), 0, stream,
                     items, time_embs, user_emb, item_emb, wf, Bf,
                     users, pos, neg, a1, a2, a3, (float*)d_out, B);
}